// Round 4
// baseline (323.953 us; speedup 1.0000x reference)
//
#include <hip/hip_runtime.h>
#include <hip/hip_bf16.h>

typedef unsigned short u16;
typedef unsigned int u32;

#define N_NODES 50000
#define N_EDGES 800000
#define DHID 256
#define ELLW 64    // ELL row stride; deg is Poisson(16), P(deg>64) ~ 1e-20
#define NSLICE 8   // feature slices (one per XCD)
#define SLICEW 32  // u16 cols per slice; slice block = 50001*64B = 3.2 MB (L2-resident)

typedef __attribute__((ext_vector_type(8))) _Float16 f16x8;
typedef __attribute__((ext_vector_type(4))) float f32x4;

// ---------- helpers ----------
__device__ __forceinline__ u16 f2bf(float f) {
    u32 u = __float_as_uint(f);
    u32 r = (u + 0x7FFFu + ((u >> 16) & 1u)) >> 16;
    return (u16)r;
}
__device__ __forceinline__ u16 f2h(float f) {
    _Float16 h = (_Float16)f;
    union { _Float16 h; u16 u; } c; c.h = h;
    return c.u;
}
__device__ __forceinline__ void gl_lds16(const void* g, void* l) {
    __builtin_amdgcn_global_load_lds(
        (const __attribute__((address_space(1))) u32*)g,
        (__attribute__((address_space(3))) u32*)l, 16, 0, 0);
}

// ---------- zero micro-kernel: deg=0 and the 8 per-slice zero rows ----------
__global__ void zero_kernel(int* __restrict__ deg, u32* __restrict__ hss32) {
    int j = blockIdx.x * 256 + threadIdx.x;
    if (j < N_NODES) deg[j] = 0;
    if (j < NSLICE * 16) {  // 8 slices x 16 u32 (=32 u16) zero row at node N_NODES
        int s = j >> 4, w = j & 15;
        hss32[((size_t)s * (N_NODES + 1) + N_NODES) * 16 + w] = 0;
    }
}

// ---------- fused prep + fill: x->f16 | W->W^T f16 | ELL fill (atomic cursor) ----------
// grid = 12500 (split) + 512 (prepw) + 3125 (fill), block 256
#define SPLIT_BLKS 12500
#define W_BLKS 512
#define FILL_BLKS 3125
__global__ void prep_fill(const float* __restrict__ x, u16* __restrict__ xf,
                          const float* __restrict__ W1, const float* __restrict__ W2,
                          u16* __restrict__ W1t, u16* __restrict__ W2t,
                          const int* __restrict__ src, const int* __restrict__ dst,
                          int* __restrict__ deg, u16* __restrict__ col16) {
    const int b = blockIdx.x, tid = threadIdx.x;
    if (b < SPLIT_BLKS) {
        int i = b * 256 + tid;  // n4 = 3.2M exact
        float4 v = ((const float4*)x)[i];
        u16 h0 = f2h(v.x), h1 = f2h(v.y), h2 = f2h(v.z), h3 = f2h(v.w);
        uint2 hv;
        hv.x = (u32)h0 | ((u32)h1 << 16);
        hv.y = (u32)h2 | ((u32)h3 << 16);
        ((uint2*)xf)[i] = hv;
    } else if (b < SPLIT_BLKS + W_BLKS) {
        int idx = b - SPLIT_BLKS;  // 0..511
        int y = idx >> 8, n = idx & 255, k = tid;
        const float* W = y ? W2 : W1;
        u16* o = y ? W2t : W1t;
        o[n * 256 + k] = f2h(W[k * 256 + n]);
    } else {
        int e = (b - SPLIT_BLKS - W_BLKS) * 256 + tid;  // 800000 exact
        int d = dst[e];
        int p = atomicAdd(&deg[d], 1);
        if (p < ELLW) col16[(size_t)d * ELLW + p] = (u16)src[e];
    }
}

// ---------- GEMM: hss[slice][row][32] = (A @ W) * rsqrt(deg[row]+1), bf16 sliced out ----------
// A f16 [Nn][256] row-major (tail clamped); W^T f16 [256][256] (n-major). K=256.
__global__ __launch_bounds__(256) void gemm_f16_kernel(
    const u16* __restrict__ Af, const u16* __restrict__ Bt,
    const int* __restrict__ deg, u16* __restrict__ hss, int M) {
    __shared__ u16 As[2][128 * 32];
    __shared__ u16 Bs[2][128 * 32];
    const int tid = threadIdx.x;
    const int wave = tid >> 6;
    const int lane = tid & 63;
    const int wm = wave >> 1, wn = wave & 1;
    const int quad = lane >> 4, l16 = lane & 15;
    const int m0 = blockIdx.x * 128;
    const int n0 = blockIdx.y * 128;

    f32x4 acc[4][4] = {};

    // staging geometry: lane fills LDS rows (tid>>2) and 64+(tid>>2), chunk tid&3.
    const int rl = tid >> 2;
    const int cl = tid & 3;
    const int kk = ((cl ^ (rl & 3) ^ ((rl >> 2) & 3)) & 3) * 8;  // swizzled source chunk
    int ar0 = m0 + rl; if (ar0 >= M) ar0 = M - 1;
    int ar1 = m0 + 64 + rl; if (ar1 >= M) ar1 = M - 1;
    const size_t aoff0 = (size_t)ar0 * 256 + kk;
    const size_t aoff1 = (size_t)ar1 * 256 + kk;
    const size_t boff0 = (size_t)(n0 + rl) * 256 + kk;
    const size_t boff1 = (size_t)(n0 + 64 + rl) * 256 + kk;
    const size_t l0 = (size_t)wave * 512;
    const size_t l1 = 2048 + (size_t)wave * 512;

    const int qs8 = ((quad ^ (l16 & 3) ^ ((l16 >> 2) & 3)) & 3) * 8;  // read-side swizzle

#define STAGE(buf, ko)                                      \
    {                                                       \
        const int koff_ = (ko) * 32;                        \
        gl_lds16(Af + aoff0 + koff_, &As[buf][l0]);         \
        gl_lds16(Af + aoff1 + koff_, &As[buf][l1]);         \
        gl_lds16(Bt + boff0 + koff_, &Bs[buf][l0]);         \
        gl_lds16(Bt + boff1 + koff_, &Bs[buf][l1]);         \
    }

    STAGE(0, 0);
    asm volatile("s_waitcnt vmcnt(0)" ::: "memory");
    __syncthreads();

    int cur = 0;
    for (int ko = 0; ko < 8; ++ko) {
        if (ko < 7) STAGE(cur ^ 1, ko + 1);

        f16x8 af[4], bf[4];
#pragma unroll
        for (int mi = 0; mi < 4; ++mi)
            af[mi] = *(const f16x8*)&As[cur][(wm * 64 + mi * 16 + l16) * 32 + qs8];
#pragma unroll
        for (int ni = 0; ni < 4; ++ni)
            bf[ni] = *(const f16x8*)&Bs[cur][(wn * 64 + ni * 16 + l16) * 32 + qs8];
#pragma unroll
        for (int mi = 0; mi < 4; ++mi)
#pragma unroll
            for (int ni = 0; ni < 4; ++ni)
                acc[mi][ni] = __builtin_amdgcn_mfma_f32_16x16x32_f16(af[mi], bf[ni], acc[mi][ni], 0, 0, 0);

        if (ko < 7) {
            asm volatile("s_waitcnt vmcnt(0)" ::: "memory");
            __syncthreads();
            cur ^= 1;
        }
    }
#undef STAGE

    // epilogue: write sliced layout hss[c>>5][row][c&31]
#pragma unroll
    for (int mi = 0; mi < 4; ++mi) {
#pragma unroll
        for (int r = 0; r < 4; ++r) {
            int row = m0 + wm * 64 + mi * 16 + quad * 4 + r;
            if (row < M) {
                float s = rsqrtf((float)deg[row] + 1.0f);
#pragma unroll
                for (int ni = 0; ni < 4; ++ni) {
                    int c = n0 + wn * 64 + ni * 16 + l16;
                    size_t o = ((size_t)(c >> 5) * (N_NODES + 1) + row) * 32 + (c & 31);
                    hss[o] = f2bf(acc[mi][ni][r] * s);
                }
            }
        }
    }
}

// ---------- sliced aggregation: block b handles slice b&7 (XCD-affine), 16 nodes ----------
// 16-lane subgroup per node; lane covers 2 bf16 cols (u32 load = one 64B line/entry/subgroup).
// Entry slot 0 = self, slots 1..cnt = ELL neighbors, padded with zero row (node Nn).
// mode 0: write f16 rows of Af (row-major, feeds next GEMM). mode 1: fp32 to d_out.
__global__ __launch_bounds__(256) void agg_kernel(
    const u16* __restrict__ hss, const u16* __restrict__ col16,
    const int* __restrict__ deg, const float* __restrict__ bias,
    u16* __restrict__ out_f16, float* __restrict__ out_f,
    int mode, int Nn) {
    const int slice = blockIdx.x & 7;
    const int chunk = blockIdx.x >> 3;
    const int wave = threadIdx.x >> 6, lane = threadIdx.x & 63;
    const int sg = lane >> 4, l16 = lane & 15;
    const int i = chunk * 16 + wave * 4 + sg;  // < 50000 exact (3125*16)
    const u16* hsS = hss + (size_t)slice * (Nn + 1) * 32;

    const int cnt = deg[i];
    const size_t ebase = (size_t)i * ELLW;
    // preload entry ids: lane l16 holds slots l16, l16+16, l16+32, l16+48
    int eA = (l16 == 0) ? i : ((l16 - 1 < cnt) ? (int)col16[ebase + l16 - 1] : Nn);
    int eB = (l16 + 15 < cnt) ? (int)col16[ebase + l16 + 15] : Nn;
    int eC = (l16 + 31 < cnt) ? (int)col16[ebase + l16 + 31] : Nn;
    int eD = (l16 + 47 < cnt) ? (int)col16[ebase + l16 + 47] : Nn;
    int entries = cnt + 1;
    if (entries > 64) entries = 64;

    float a0 = 0.f, a1 = 0.f;
    const int lbase = sg * 16;
    const int lofs = l16 * 2;

#define BATCH(v, q)                                                             \
    {                                                                           \
        int e0 = __shfl((v), lbase + (q) * 4 + 0, 64);                          \
        int e1 = __shfl((v), lbase + (q) * 4 + 1, 64);                          \
        int e2 = __shfl((v), lbase + (q) * 4 + 2, 64);                          \
        int e3 = __shfl((v), lbase + (q) * 4 + 3, 64);                          \
        u32 v0 = *(const u32*)(hsS + (size_t)e0 * 32 + lofs);                   \
        u32 v1 = *(const u32*)(hsS + (size_t)e1 * 32 + lofs);                   \
        u32 v2 = *(const u32*)(hsS + (size_t)e2 * 32 + lofs);                   \
        u32 v3 = *(const u32*)(hsS + (size_t)e3 * 32 + lofs);                   \
        a0 += __uint_as_float(v0 << 16);  a1 += __uint_as_float(v0 & 0xffff0000u); \
        a0 += __uint_as_float(v1 << 16);  a1 += __uint_as_float(v1 & 0xffff0000u); \
        a0 += __uint_as_float(v2 << 16);  a1 += __uint_as_float(v2 & 0xffff0000u); \
        a0 += __uint_as_float(v3 << 16);  a1 += __uint_as_float(v3 & 0xffff0000u); \
    }

#pragma unroll
    for (int r = 0; r < 4; ++r) {
        int v = (r == 0) ? eA : (r == 1) ? eB : (r == 2) ? eC : eD;
#pragma unroll
        for (int q = 0; q < 4; ++q) {
            int gs = r * 16 + q * 4;
            if (gs < entries) BATCH(v, q);
        }
    }
#undef BATCH

    const float inv = rsqrtf((float)cnt + 1.0f);
    float2 bb = *(const float2*)(bias + slice * 32 + lofs);
    float r0 = fmaxf(fmaf(a0, inv, bb.x), 0.0f);
    float r1 = fmaxf(fmaf(a1, inv, bb.y), 0.0f);
    const size_t o = (size_t)i * 256 + slice * 32 + lofs;
    if (mode == 0) {
        u32 w = (u32)f2h(r0) | ((u32)f2h(r1) << 16);
        *(u32*)(out_f16 + o) = w;
    } else {
        *(float2*)(out_f + o) = make_float2(r0, r1);
    }
}

extern "C" void kernel_launch(void* const* d_in, const int* in_sizes, int n_in,
                              void* d_out, int out_size, void* d_ws, size_t ws_size,
                              hipStream_t stream) {
    const float* x = (const float*)d_in[0];
    const int* ei = (const int*)d_in[1];
    const float* W1 = (const float*)d_in[2];
    const float* b1 = (const float*)d_in[3];
    const float* W2 = (const float*)d_in[4];
    const float* b2 = (const float*)d_in[5];
    float* out = (float*)d_out;

    const int Nn = N_NODES, E = N_EDGES;
    const int* srcp = ei;
    const int* dstp = ei + E;

    // d_out doubles as scratch: f16 GEMM A buffer (25.6 MB of the 51.2 MB).
    u16* Af = (u16*)d_out;

    char* p = (char*)d_ws;
    auto take = [&](size_t bytes) -> void* {
        void* r = (void*)p;
        p += (bytes + 255) & ~(size_t)255;
        return r;
    };
    u16* hss   = (u16*)take((size_t)NSLICE * (Nn + 1) * SLICEW * 2);  // sliced bf16 h, 25.6 MB
    u16* col16 = (u16*)take((size_t)Nn * ELLW * 2);                   // ELL, 6.4 MB
    int* deg   = (int*)take((size_t)Nn * 4);
    u16* W1t   = (u16*)take(256 * 256 * 2);
    u16* W2t   = (u16*)take(256 * 256 * 2);

    zero_kernel<<<196, 256, 0, stream>>>(deg, (u32*)hss);
    prep_fill<<<SPLIT_BLKS + W_BLKS + FILL_BLKS, 256, 0, stream>>>(
        x, Af, W1, W2, W1t, W2t, srcp, dstp, deg, col16);

    const int gm = (Nn + 127) / 128;  // 391
    const int ga = (Nn / 16) * NSLICE;  // 25000
    // layer 1
    gemm_f16_kernel<<<dim3(gm, 2), 256, 0, stream>>>(Af, W1t, deg, hss, Nn);
    agg_kernel<<<ga, 256, 0, stream>>>(hss, col16, deg, b1, Af, nullptr, 0, Nn);
    // layer 2
    gemm_f16_kernel<<<dim3(gm, 2), 256, 0, stream>>>(Af, W2t, deg, hss, Nn);
    agg_kernel<<<ga, 256, 0, stream>>>(hss, col16, deg, b2, nullptr, out, 1, Nn);
}